// Round 3
// baseline (628.518 us; speedup 1.0000x reference)
//
#include <hip/hip_runtime.h>
#include <hip/hip_bf16.h>

typedef unsigned short u16;
typedef unsigned long long u64;
typedef __bf16 bf16x8 __attribute__((ext_vector_type(8)));
typedef float f32x4 __attribute__((ext_vector_type(4)));

#define AS1 __attribute__((address_space(1)))
#define AS3 __attribute__((address_space(3)))
#define GLL16(gp, lp) __builtin_amdgcn_global_load_lds((AS1 const unsigned int*)(gp), (AS3 unsigned int*)(lp), 16, 0, 0)

__device__ __forceinline__ u16 f2bf(float f) {
    unsigned u = __builtin_bit_cast(unsigned, f);
    unsigned r = u + 0x7FFFu + ((u >> 16) & 1u);
    return (u16)(r >> 16);
}

// ---------------- mask dtype detector ----------------
// flag: 0=u8(bool), 1=i32, 2=f32, 3=bf16
__global__ void detect_kernel(const unsigned char* __restrict__ m, int* __restrict__ flag) {
    __shared__ int cnt1;
    __shared__ int big;
    if (threadIdx.x == 0) { cnt1 = 0; big = 0; }
    __syncthreads();
    int c1 = 0, bg = 0;
    for (int i = threadIdx.x; i < 16384; i += 256) {
        unsigned char v = m[i];
        if (v) {
            if ((i & 3) == 1) c1++;
            if (v > 1) bg++;
        }
    }
    atomicAdd(&cnt1, c1);
    atomicAdd(&big, bg);
    __syncthreads();
    if (threadIdx.x == 0) {
        int f;
        if (big == 0) f = cnt1 ? 0 : 1;
        else          f = cnt1 ? 3 : 2;
        *flag = f;
    }
}

// ---------------- mask -> packed bitmask (bit L = k-col L within 64-tile) ----------------
#define MN_LOOP(PRED)                                                     \
    for (int row = wave; row < 65536; row += nw) {                        \
        size_t base = (size_t)row * 1024;                                 \
        u64 myw = 0;                                                      \
        _Pragma("unroll")                                                 \
        for (int kb = 0; kb < 16; ++kb) {                                 \
            size_t gi = base + kb * 64 + lane;                            \
            bool p = (PRED);                                              \
            u64 w = __ballot(p);                                          \
            if (lane == kb) myw = w;                                      \
        }                                                                 \
        if (lane < 16) MB[(size_t)row * 16 + lane] = myw;                 \
    }

__global__ __launch_bounds__(256) void masknorm_kernel(const void* __restrict__ mp,
                                                       const int* __restrict__ flagp,
                                                       u64* __restrict__ MB) {
    const int flag = *flagp;
    const int lane = threadIdx.x & 63;
    const int wave = blockIdx.x * 4 + (threadIdx.x >> 6);
    const int nw = gridDim.x * 4;
    if (flag == 0) {
        const unsigned char* m8 = (const unsigned char*)mp;
        MN_LOOP(m8[gi] != 0)
    } else if (flag == 1) {
        const int* m32 = (const int*)mp;
        MN_LOOP(m32[gi] != 0)
    } else if (flag == 2) {
        const unsigned* mf = (const unsigned*)mp;
        MN_LOOP((mf[gi] << 1) != 0)
    } else {
        const u16* mb = (const u16*)mp;
        MN_LOOP((mb[gi] & 0x7FFF) != 0)
    }
}

// ---------------- f32 -> bf16 cast of Q/K/V inputs ----------------
__global__ void cast3_kernel(const float* __restrict__ q, const float* __restrict__ k,
                             const float* __restrict__ v, u16* __restrict__ xq,
                             u16* __restrict__ xk, u16* __restrict__ xv) {
    const int n4 = 4 * 1024 * 1024 / 4;
    int stride = gridDim.x * blockDim.x;
    for (int i = blockIdx.x * blockDim.x + threadIdx.x; i < n4; i += stride) {
        float4 a = ((const float4*)q)[i];
        float4 b = ((const float4*)k)[i];
        float4 c = ((const float4*)v)[i];
        ((ushort4*)xq)[i] = make_ushort4(f2bf(a.x), f2bf(a.y), f2bf(a.z), f2bf(a.w));
        ((ushort4*)xk)[i] = make_ushort4(f2bf(b.x), f2bf(b.y), f2bf(b.z), f2bf(b.w));
        ((ushort4*)xv)[i] = make_ushort4(f2bf(c.x), f2bf(c.y), f2bf(c.z), f2bf(c.w));
    }
}

// ---------------- weight transpose + cast ----------------
__global__ __launch_bounds__(256) void wtrans_kernel(
    const float* __restrict__ W0, const float* __restrict__ W1,
    const float* __restrict__ W2, const float* __restrict__ W3,
    u16* __restrict__ T0, u16* __restrict__ T1, u16* __restrict__ T2, u16* __restrict__ T3) {
    const float* W = (blockIdx.z == 0) ? W0 : (blockIdx.z == 1) ? W1 : (blockIdx.z == 2) ? W2 : W3;
    u16* T = (blockIdx.z == 0) ? T0 : (blockIdx.z == 1) ? T1 : (blockIdx.z == 2) ? T2 : T3;
    __shared__ float t[64][65];
    const int n0 = blockIdx.x * 64, k0 = blockIdx.y * 64;
    const int tx = threadIdx.x, ty = threadIdx.y;
    for (int j = ty; j < 64; j += 4) t[j][tx] = W[(size_t)(k0 + j) * 1024 + n0 + tx];
    __syncthreads();
    for (int j = ty; j < 64; j += 4) T[(size_t)(n0 + j) * 1024 + k0 + tx] = f2bf(t[tx][j]);
}

// ---------------- GEMM: C = A(M,K) @ Bt(N,K)^T + bias, bf16 MFMA ----------------
template <int MODE>
__global__ __launch_bounds__(256) void gemm_bt(
    const u16* __restrict__ A, const u16* __restrict__ Bt, const float* __restrict__ bias,
    void* __restrict__ outp, const float* __restrict__ resid, int M, int N, int K, float scale) {
    __shared__ __align__(16) u16 lsA[128 * 64];
    __shared__ __align__(16) u16 lsB[128 * 64];
    const int tid = threadIdx.x, lane = tid & 63, wid = tid >> 6;
    const int bm = blockIdx.y, bn = blockIdx.x;
    const int wr = wid >> 1, wc = wid & 1;
    const int l15 = lane & 15, l4 = lane >> 4;
    f32x4 acc[4][4] = {};
    const int cbase = wid * 256;
    const int nt = K >> 6;
    for (int t = 0; t < nt; ++t) {
        __syncthreads();
        for (int j = 0; j < 4; ++j) {
            int c = cbase + j * 64 + lane;
            int row = c >> 3, off = (c & 7) * 8;
            const u16* ga = A + (size_t)(bm * 128 + row) * K + t * 64 + off;
            GLL16(ga, lsA + (size_t)(cbase + j * 64) * 8);
            const u16* gb = Bt + (size_t)(bn * 128 + row) * K + t * 64 + off;
            GLL16(gb, lsB + (size_t)(cbase + j * 64) * 8);
        }
        __syncthreads();
        for (int kk = 0; kk < 2; ++kk) {
            bf16x8 af[4], bfr[4];
            for (int m = 0; m < 4; ++m)
                af[m] = *(const bf16x8*)(lsA + (wr * 64 + m * 16 + l15) * 64 + kk * 32 + l4 * 8);
            for (int n = 0; n < 4; ++n)
                bfr[n] = *(const bf16x8*)(lsB + (wc * 64 + n * 16 + l15) * 64 + kk * 32 + l4 * 8);
            for (int m = 0; m < 4; ++m)
                for (int n = 0; n < 4; ++n)
                    acc[m][n] = __builtin_amdgcn_mfma_f32_16x16x32_bf16(af[m], bfr[n], acc[m][n], 0, 0, 0);
        }
    }
    for (int n = 0; n < 4; ++n) {
        int c = bn * 128 + wc * 64 + n * 16 + l15;
        float bv = bias[c];
        for (int m = 0; m < 4; ++m) {
            for (int j = 0; j < 4; ++j) {
                int r = bm * 128 + wr * 64 + m * 16 + l4 * 4 + j;
                float v = acc[m][n][j];
                if (MODE == 0) {
                    ((u16*)outp)[(size_t)r * N + c] = f2bf((v + bv) * scale);
                } else if (MODE == 1) {
                    int bb = r >> 10, k = r & 1023, h = c >> 6, d = c & 63;
                    ((u16*)outp)[((size_t)((bb * 16 + h) * 64 + d)) * 1024 + k] = f2bf(v + bv);
                } else {
                    ((float*)outp)[(size_t)r * N + c] = v + bv + resid[(size_t)r * N + c];
                }
            }
        }
    }
}

// ---------------- fused geometry attention (reg-prefetched geometry, barrier-free k-loop) ----------------
// K-column permutation: MFMA fragment nf, lane l15 owns k-col (l15*4+nf) of each 64-tile,
// so geometry is one float4/row and mask bits are a nibble. K rows loaded permuted to match;
// P is written to pbuf in natural k-order so PV is unchanged.
__global__ __launch_bounds__(256) void attn_kernel(
    const u16* __restrict__ Qs, const u16* __restrict__ Ks, const u16* __restrict__ Vt,
    const float* __restrict__ geom, const u64* __restrict__ MB,
    u16* __restrict__ AO) {
    __shared__ u64 mw[64 * 17];                 // mask words, padded stride 17
    __shared__ __align__(16) u16 pbuf[4][16][72];

    // XCD-aware decode: the 16 q-blocks sharing (b,h) K/V land on the same XCD
    const int g = blockIdx.x;
    const int t = (g & 7) * 128 + (g >> 3);
    const int qb = t & 15;
    const int bhid = t >> 4;
    const int b = bhid >> 4, h = bhid & 15;
    const int q0 = qb * 64;

    const int tid = threadIdx.x, lane = tid & 63, wid = tid >> 6;
    const int l15 = lane & 15, l4 = lane >> 4;
    const int qrow = q0 + wid * 16;
    const size_t bh = (size_t)bhid;

    const u16* qp = Qs + (size_t)(b * 1024 + qrow + l15) * 1024 + h * 64 + l4 * 8;
    bf16x8 aq0 = *(const bf16x8*)qp;
    bf16x8 aq1 = *(const bf16x8*)(qp + 32);

    // stage mask words once (64 rows x 16 words)
    for (int u = tid; u < 1024; u += 256) {
        int r = u >> 4, w = u & 15;
        mw[r * 17 + w] = MB[(bh * 1024 + q0 + r) * 16 + w];
    }
    __syncthreads();

    f32x4 o[4] = {};
    float m_run[4], l_run[4];
    for (int j = 0; j < 4; ++j) { m_run[j] = -1e30f; l_run[j] = 0.f; }

    // per-thread geometry base: row (qrow + l4*4 + j), col (kb*64 + l15*4 ..+3)
    const float* gbase = geom + (bh * 1024 + qrow + l4 * 4) * 1024 + l15 * 4;
    f32x4 gp[2][4];
#pragma unroll
    for (int j = 0; j < 4; ++j) gp[0][j] = *(const f32x4*)(gbase + j * 1024);

    const int mrow = wid * 16 + l4 * 4;
    const int mshift = l15 * 4;

#pragma unroll
    for (int kb = 0; kb < 16; ++kb) {
        const int cur = kb & 1;
        // prefetch next geometry tile into the other register buffer
        if (kb < 15) {
#pragma unroll
            for (int j = 0; j < 4; ++j)
                gp[cur ^ 1][j] = *(const f32x4*)(gbase + j * 1024 + (kb + 1) * 64);
        }

        // QK^T (K rows permuted: fragment nf col l15 <- k-row l15*4+nf)
        f32x4 s[4];
#pragma unroll
        for (int nf = 0; nf < 4; ++nf) {
            const u16* kp = Ks + (size_t)(b * 1024 + kb * 64 + l15 * 4 + nf) * 1024 + h * 64 + l4 * 8;
            bf16x8 k0 = *(const bf16x8*)kp;
            bf16x8 k1 = *(const bf16x8*)(kp + 32);
            f32x4 z = {};
            z = __builtin_amdgcn_mfma_f32_16x16x32_bf16(aq0, k0, z, 0, 0, 0);
            s[nf] = __builtin_amdgcn_mfma_f32_16x16x32_bf16(aq1, k1, z, 0, 0, 0);
        }

        // geometry log-bias + mask (registers + one LDS broadcast word per row)
#pragma unroll
        for (int j = 0; j < 4; ++j) {
            const u64 mword = mw[(mrow + j) * 17 + kb];
            const unsigned mnib = (unsigned)(mword >> mshift);
            f32x4 gv = gp[cur][j];
#pragma unroll
            for (int nf = 0; nf < 4; ++nf) {
                bool msk = (mnib >> nf) & 1u;
                s[nf][j] = msk ? -1e30f : (s[nf][j] + __logf(fmaxf(gv[nf], 1e-6f)));
            }
        }

        // online softmax (row-groups of 16 lanes)
        float scl[4];
#pragma unroll
        for (int j = 0; j < 4; ++j) {
            float mt = fmaxf(fmaxf(s[0][j], s[1][j]), fmaxf(s[2][j], s[3][j]));
            for (int d = 1; d < 16; d <<= 1) mt = fmaxf(mt, __shfl_xor(mt, d, 16));
            float mn = fmaxf(m_run[j], mt);
            scl[j] = __expf(m_run[j] - mn);
            float rs = 0.f;
            for (int nf = 0; nf < 4; ++nf) {
                float p = __expf(s[nf][j] - mn);
                s[nf][j] = p;
                rs += p;
            }
            for (int d = 1; d < 16; d <<= 1) rs += __shfl_xor(rs, d, 16);
            l_run[j] = l_run[j] * scl[j] + rs;
            m_run[j] = mn;
        }
#pragma unroll
        for (int df = 0; df < 4; ++df) {
            f32x4 tt = o[df];
            for (int j = 0; j < 4; ++j) tt[j] *= scl[j];
            o[df] = tt;
        }

        // P -> pbuf: thread holds P[l4*4+j][l15*4+nf]; pack 4 bf16 -> one ds_write_b64
#pragma unroll
        for (int j = 0; j < 4; ++j) {
            u64 pk = (u64)f2bf(s[0][j]) | ((u64)f2bf(s[1][j]) << 16) |
                     ((u64)f2bf(s[2][j]) << 32) | ((u64)f2bf(s[3][j]) << 48);
            *(u64*)((char*)&pbuf[wid][l4 * 4 + j][0] + l15 * 8) = pk;
        }
        bf16x8 pa0 = *(const bf16x8*)&pbuf[wid][l15][l4 * 8];
        bf16x8 pa1 = *(const bf16x8*)&pbuf[wid][l15][32 + l4 * 8];
#pragma unroll
        for (int df = 0; df < 4; ++df) {
            const u16* vp = Vt + (bh * 64 + df * 16 + l15) * 1024 + (size_t)kb * 64 + l4 * 8;
            bf16x8 v0 = *(const bf16x8*)vp;
            bf16x8 v1 = *(const bf16x8*)(vp + 32);
            o[df] = __builtin_amdgcn_mfma_f32_16x16x32_bf16(pa0, v0, o[df], 0, 0, 0);
            o[df] = __builtin_amdgcn_mfma_f32_16x16x32_bf16(pa1, v1, o[df], 0, 0, 0);
        }
    }
#pragma unroll
    for (int df = 0; df < 4; ++df)
        for (int j = 0; j < 4; ++j) {
            int r = b * 1024 + qrow + l4 * 4 + j;
            int c = h * 64 + df * 16 + l15;
            AO[(size_t)r * 1024 + c] = f2bf(o[df][j] / l_run[j]);
        }
}

// ---------------- LayerNorm over rows of Y (f32) ----------------
__global__ __launch_bounds__(256) void ln_kernel(const float* __restrict__ Y,
                                                 const float* __restrict__ gamma,
                                                 const float* __restrict__ beta,
                                                 float* __restrict__ out) {
    __shared__ float red[8];
    const int r = blockIdx.x, tid = threadIdx.x, lane = tid & 63, wid = tid >> 6;
    float4 v = ((const float4*)(Y + (size_t)r * 1024))[tid];
    float s = v.x + v.y + v.z + v.w;
    float q = v.x * v.x + v.y * v.y + v.z * v.z + v.w * v.w;
    for (int d = 1; d < 64; d <<= 1) {
        s += __shfl_xor(s, d, 64);
        q += __shfl_xor(q, d, 64);
    }
    if (lane == 0) { red[wid] = s; red[4 + wid] = q; }
    __syncthreads();
    float ts = red[0] + red[1] + red[2] + red[3];
    float tq = red[4] + red[5] + red[6] + red[7];
    float mu = ts * (1.f / 1024.f);
    float var = tq * (1.f / 1024.f) - mu * mu;
    float rstd = rsqrtf(var + 1e-5f);
    float4 g = ((const float4*)gamma)[tid];
    float4 be = ((const float4*)beta)[tid];
    float4 ov;
    ov.x = (v.x - mu) * rstd * g.x + be.x;
    ov.y = (v.y - mu) * rstd * g.y + be.y;
    ov.z = (v.z - mu) * rstd * g.z + be.z;
    ov.w = (v.w - mu) * rstd * g.w + be.w;
    ((float4*)(out + (size_t)r * 1024))[tid] = ov;
}

extern "C" void kernel_launch(void* const* d_in, const int* in_sizes, int n_in,
                              void* d_out, int out_size, void* d_ws, size_t ws_size,
                              hipStream_t stream) {
    const float* queries = (const float*)d_in[0];
    const float* keys    = (const float*)d_in[1];
    const float* values  = (const float*)d_in[2];
    const float* geom    = (const float*)d_in[3];
    const void*  mask    = d_in[4];
    const float* Wq = (const float*)d_in[5];  const float* bq = (const float*)d_in[6];
    const float* Wk = (const float*)d_in[7];  const float* bk = (const float*)d_in[8];
    const float* Wv = (const float*)d_in[9];  const float* bv = (const float*)d_in[10];
    const float* Wo = (const float*)d_in[11]; const float* bo = (const float*)d_in[12];
    const float* gamma = (const float*)d_in[13];
    const float* beta  = (const float*)d_in[14];

    char* ws = (char*)d_ws;
    const size_t MB_ = 1024 * 1024;
    u16* XQ  = (u16*)(ws + 0);
    u16* XK  = (u16*)(ws + 8 * MB_);
    u16* XV  = (u16*)(ws + 16 * MB_);
    u16* WQT = (u16*)(ws + 24 * MB_);
    u16* WKT = (u16*)(ws + 26 * MB_);
    u16* WVT = (u16*)(ws + 28 * MB_);
    u16* WOT = (u16*)(ws + 30 * MB_);
    u16* QS  = (u16*)(ws + 32 * MB_);
    u16* KS  = (u16*)(ws + 40 * MB_);
    u16* VT  = (u16*)(ws + 48 * MB_);
    u16* AO  = (u16*)(ws + 56 * MB_);
    u64* MBITS = (u64*)(ws + 16 * MB_);  // reuses XV (dead after V GEMM)
    float* Y = (float*)(ws + 0);         // reuses XQ/XK region (dead by then)
    int* FLAG = (int*)(ws + 64 * MB_);

    detect_kernel<<<1, 256, 0, stream>>>((const unsigned char*)mask, FLAG);
    cast3_kernel<<<1024, 256, 0, stream>>>(queries, keys, values, XQ, XK, XV);
    wtrans_kernel<<<dim3(16, 16, 4), dim3(64, 4), 0, stream>>>(Wq, Wk, Wv, Wo, WQT, WKT, WVT, WOT);
    gemm_bt<0><<<dim3(8, 32), 256, 0, stream>>>(XQ, WQT, bq, QS, nullptr, 4096, 1024, 1024, 0.125f);
    gemm_bt<0><<<dim3(8, 32), 256, 0, stream>>>(XK, WKT, bk, KS, nullptr, 4096, 1024, 1024, 1.0f);
    gemm_bt<1><<<dim3(8, 32), 256, 0, stream>>>(XV, WVT, bv, VT, nullptr, 4096, 1024, 1024, 1.0f);
    masknorm_kernel<<<4096, 256, 0, stream>>>(mask, FLAG, MBITS);
    attn_kernel<<<1024, 256, 0, stream>>>(QS, KS, VT, geom, MBITS, AO);
    gemm_bt<2><<<dim3(8, 32), 256, 0, stream>>>(AO, WOT, bo, Y, queries, 4096, 1024, 1024, 1.0f);
    ln_kernel<<<4096, 256, 0, stream>>>(Y, gamma, beta, (float*)d_out);
}

// Round 4
// 354.632 us; speedup vs baseline: 1.7723x; 1.7723x over previous
//
#include <hip/hip_runtime.h>
#include <hip/hip_bf16.h>

typedef unsigned short u16;
typedef unsigned long long u64;
typedef __bf16 bf16x8 __attribute__((ext_vector_type(8)));
typedef float f32x4 __attribute__((ext_vector_type(4)));

#define AS1 __attribute__((address_space(1)))
#define AS3 __attribute__((address_space(3)))
#define GLL16(gp, lp) __builtin_amdgcn_global_load_lds((AS1 const unsigned int*)(gp), (AS3 unsigned int*)(lp), 16, 0, 0)

__device__ __forceinline__ u16 f2bf(float f) {
    unsigned u = __builtin_bit_cast(unsigned, f);
    unsigned r = u + 0x7FFFu + ((u >> 16) & 1u);
    return (u16)(r >> 16);
}

// ---------------- mask dtype detector ----------------
// flag: 0=u8(bool), 1=i32, 2=f32, 3=bf16
__global__ void detect_kernel(const unsigned char* __restrict__ m, int* __restrict__ flag) {
    __shared__ int cnt1;
    __shared__ int big;
    if (threadIdx.x == 0) { cnt1 = 0; big = 0; }
    __syncthreads();
    int c1 = 0, bg = 0;
    for (int i = threadIdx.x; i < 16384; i += 256) {
        unsigned char v = m[i];
        if (v) {
            if ((i & 3) == 1) c1++;
            if (v > 1) bg++;
        }
    }
    atomicAdd(&cnt1, c1);
    atomicAdd(&big, bg);
    __syncthreads();
    if (threadIdx.x == 0) {
        int f;
        if (big == 0) f = cnt1 ? 0 : 1;
        else          f = cnt1 ? 3 : 2;
        *flag = f;
    }
}

// ---------------- mask -> packed bitmask (bit L = k-col L within 64-tile) ----------------
#define MN_LOOP(PRED)                                                     \
    for (int row = wave; row < 65536; row += nw) {                        \
        size_t base = (size_t)row * 1024;                                 \
        u64 myw = 0;                                                      \
        _Pragma("unroll")                                                 \
        for (int kb = 0; kb < 16; ++kb) {                                 \
            size_t gi = base + kb * 64 + lane;                            \
            bool p = (PRED);                                              \
            u64 w = __ballot(p);                                          \
            if (lane == kb) myw = w;                                      \
        }                                                                 \
        if (lane < 16) MB[(size_t)row * 16 + lane] = myw;                 \
    }

__global__ __launch_bounds__(256) void masknorm_kernel(const void* __restrict__ mp,
                                                       const int* __restrict__ flagp,
                                                       u64* __restrict__ MB) {
    const int flag = *flagp;
    const int lane = threadIdx.x & 63;
    const int wave = blockIdx.x * 4 + (threadIdx.x >> 6);
    const int nw = gridDim.x * 4;
    if (flag == 0) {
        const unsigned char* m8 = (const unsigned char*)mp;
        MN_LOOP(m8[gi] != 0)
    } else if (flag == 1) {
        const int* m32 = (const int*)mp;
        MN_LOOP(m32[gi] != 0)
    } else if (flag == 2) {
        const unsigned* mf = (const unsigned*)mp;
        MN_LOOP((mf[gi] << 1) != 0)
    } else {
        const u16* mb = (const u16*)mp;
        MN_LOOP((mb[gi] & 0x7FFF) != 0)
    }
}

// ---------------- f32 -> bf16 cast of Q/K/V inputs ----------------
__global__ void cast3_kernel(const float* __restrict__ q, const float* __restrict__ k,
                             const float* __restrict__ v, u16* __restrict__ xq,
                             u16* __restrict__ xk, u16* __restrict__ xv) {
    const int n4 = 4 * 1024 * 1024 / 4;
    int stride = gridDim.x * blockDim.x;
    for (int i = blockIdx.x * blockDim.x + threadIdx.x; i < n4; i += stride) {
        float4 a = ((const float4*)q)[i];
        float4 b = ((const float4*)k)[i];
        float4 c = ((const float4*)v)[i];
        ((ushort4*)xq)[i] = make_ushort4(f2bf(a.x), f2bf(a.y), f2bf(a.z), f2bf(a.w));
        ((ushort4*)xk)[i] = make_ushort4(f2bf(b.x), f2bf(b.y), f2bf(b.z), f2bf(b.w));
        ((ushort4*)xv)[i] = make_ushort4(f2bf(c.x), f2bf(c.y), f2bf(c.z), f2bf(c.w));
    }
}

// ---------------- weight transpose + cast ----------------
__global__ __launch_bounds__(256) void wtrans_kernel(
    const float* __restrict__ W0, const float* __restrict__ W1,
    const float* __restrict__ W2, const float* __restrict__ W3,
    u16* __restrict__ T0, u16* __restrict__ T1, u16* __restrict__ T2, u16* __restrict__ T3) {
    const float* W = (blockIdx.z == 0) ? W0 : (blockIdx.z == 1) ? W1 : (blockIdx.z == 2) ? W2 : W3;
    u16* T = (blockIdx.z == 0) ? T0 : (blockIdx.z == 1) ? T1 : (blockIdx.z == 2) ? T2 : T3;
    __shared__ float t[64][65];
    const int n0 = blockIdx.x * 64, k0 = blockIdx.y * 64;
    const int tx = threadIdx.x, ty = threadIdx.y;
    for (int j = ty; j < 64; j += 4) t[j][tx] = W[(size_t)(k0 + j) * 1024 + n0 + tx];
    __syncthreads();
    for (int j = ty; j < 64; j += 4) T[(size_t)(n0 + j) * 1024 + k0 + tx] = f2bf(t[tx][j]);
}

// ---------------- merged QKV GEMM: z=0 Q (scaled), z=1 K, z=2 V (transposed out) ----------------
__global__ __launch_bounds__(256) void qkv_gemm(
    const u16* __restrict__ XQ, const u16* __restrict__ XK, const u16* __restrict__ XV,
    const u16* __restrict__ WQT, const u16* __restrict__ WKT, const u16* __restrict__ WVT,
    const float* __restrict__ bq, const float* __restrict__ bk, const float* __restrict__ bv,
    u16* __restrict__ QS, u16* __restrict__ KS, u16* __restrict__ VT) {
    __shared__ __align__(16) u16 lsA[128 * 64];
    __shared__ __align__(16) u16 lsB[128 * 64];
    const int z = blockIdx.z;
    const u16* A  = (z == 0) ? XQ : (z == 1) ? XK : XV;
    const u16* Bt = (z == 0) ? WQT : (z == 1) ? WKT : WVT;
    const float* bias = (z == 0) ? bq : (z == 1) ? bk : bv;
    const int tid = threadIdx.x, lane = tid & 63, wid = tid >> 6;
    const int bm = blockIdx.y, bn = blockIdx.x;
    const int wr = wid >> 1, wc = wid & 1;
    const int l15 = lane & 15, l4 = lane >> 4;
    f32x4 acc[4][4] = {};
    const int cbase = wid * 256;
    for (int t = 0; t < 16; ++t) {
        __syncthreads();
        for (int j = 0; j < 4; ++j) {
            int c = cbase + j * 64 + lane;
            int row = c >> 3, off = (c & 7) * 8;
            GLL16(A + (size_t)(bm * 128 + row) * 1024 + t * 64 + off, lsA + (size_t)(cbase + j * 64) * 8);
            GLL16(Bt + (size_t)(bn * 128 + row) * 1024 + t * 64 + off, lsB + (size_t)(cbase + j * 64) * 8);
        }
        __syncthreads();
        for (int kk = 0; kk < 2; ++kk) {
            bf16x8 af[4], bfr[4];
            for (int m = 0; m < 4; ++m)
                af[m] = *(const bf16x8*)(lsA + (wr * 64 + m * 16 + l15) * 64 + kk * 32 + l4 * 8);
            for (int n = 0; n < 4; ++n)
                bfr[n] = *(const bf16x8*)(lsB + (wc * 64 + n * 16 + l15) * 64 + kk * 32 + l4 * 8);
            for (int m = 0; m < 4; ++m)
                for (int n = 0; n < 4; ++n)
                    acc[m][n] = __builtin_amdgcn_mfma_f32_16x16x32_bf16(af[m], bfr[n], acc[m][n], 0, 0, 0);
        }
    }
    const float scale = (z == 0) ? 0.125f : 1.0f;
    for (int n = 0; n < 4; ++n) {
        int c = bn * 128 + wc * 64 + n * 16 + l15;
        float bv_ = bias[c];
        for (int m = 0; m < 4; ++m) {
            for (int j = 0; j < 4; ++j) {
                int r = bm * 128 + wr * 64 + m * 16 + l4 * 4 + j;
                float v = acc[m][n][j];
                if (z == 2) {
                    int bb = r >> 10, k = r & 1023, h = c >> 6, d = c & 63;
                    VT[((size_t)((bb * 16 + h) * 64 + d)) * 1024 + k] = f2bf(v + bv_);
                } else {
                    u16* outp = (z == 0) ? QS : KS;
                    outp[(size_t)r * 1024 + c] = f2bf((v + bv_) * scale);
                }
            }
        }
    }
}

// ---------------- output-projection GEMM (+bias +residual, f32 out) ----------------
__global__ __launch_bounds__(256) void gemm_out(
    const u16* __restrict__ A, const u16* __restrict__ Bt, const float* __restrict__ bias,
    float* __restrict__ outp, const float* __restrict__ resid) {
    __shared__ __align__(16) u16 lsA[128 * 64];
    __shared__ __align__(16) u16 lsB[128 * 64];
    const int tid = threadIdx.x, lane = tid & 63, wid = tid >> 6;
    const int bm = blockIdx.y, bn = blockIdx.x;
    const int wr = wid >> 1, wc = wid & 1;
    const int l15 = lane & 15, l4 = lane >> 4;
    f32x4 acc[4][4] = {};
    const int cbase = wid * 256;
    for (int t = 0; t < 16; ++t) {
        __syncthreads();
        for (int j = 0; j < 4; ++j) {
            int c = cbase + j * 64 + lane;
            int row = c >> 3, off = (c & 7) * 8;
            GLL16(A + (size_t)(bm * 128 + row) * 1024 + t * 64 + off, lsA + (size_t)(cbase + j * 64) * 8);
            GLL16(Bt + (size_t)(bn * 128 + row) * 1024 + t * 64 + off, lsB + (size_t)(cbase + j * 64) * 8);
        }
        __syncthreads();
        for (int kk = 0; kk < 2; ++kk) {
            bf16x8 af[4], bfr[4];
            for (int m = 0; m < 4; ++m)
                af[m] = *(const bf16x8*)(lsA + (wr * 64 + m * 16 + l15) * 64 + kk * 32 + l4 * 8);
            for (int n = 0; n < 4; ++n)
                bfr[n] = *(const bf16x8*)(lsB + (wc * 64 + n * 16 + l15) * 64 + kk * 32 + l4 * 8);
            for (int m = 0; m < 4; ++m)
                for (int n = 0; n < 4; ++n)
                    acc[m][n] = __builtin_amdgcn_mfma_f32_16x16x32_bf16(af[m], bfr[n], acc[m][n], 0, 0, 0);
        }
    }
    for (int n = 0; n < 4; ++n) {
        int c = bn * 128 + wc * 64 + n * 16 + l15;
        float bv = bias[c];
        for (int m = 0; m < 4; ++m)
            for (int j = 0; j < 4; ++j) {
                int r = bm * 128 + wr * 64 + m * 16 + l4 * 4 + j;
                outp[(size_t)r * 1024 + c] = acc[m][n][j] + bv + resid[(size_t)r * 1024 + c];
            }
    }
}

// ---------------- fused geometry attention v3 ----------------
// K/V tiles double-buffered in LDS (1-tile-ahead pipeline, 1 barrier/tile).
// Geometry: per-thread f32x4 register prefetch (named A/B bufs, 8x2 unrolled loop).
// K-col permutation: fragment nf, lane l15 owns k-col l15*4+nf (coalesced geom).
// K LDS row r holds global k-row (r&15)*4+(r>>4); slots XOR-swizzled by row&7.
__device__ __forceinline__ void stage_kv(u16* lsbuf, const u16* Ks, const u16* Vt,
                                         int b, int h, size_t bh, int kb, int wid, int lane) {
#pragma unroll
    for (int part = 0; part < 2; ++part) {
        int cc = part * 256 + wid * 64 + lane;
        int r = cc >> 3, s = cc & 7;
        int gr = (r & 15) * 4 + (r >> 4);
        const u16* src = Ks + (size_t)(b * 1024 + kb * 64 + gr) * 1024 + h * 64 + ((s ^ (r & 7)) * 8);
        GLL16(src, lsbuf + (part * 256 + wid * 64) * 8);
    }
#pragma unroll
    for (int part = 0; part < 2; ++part) {
        int cc = part * 256 + wid * 64 + lane;
        int r = cc >> 3, s = cc & 7;
        const u16* src = Vt + (bh * 64 + r) * 1024 + (size_t)kb * 64 + ((s ^ (r & 7)) * 8);
        GLL16(src, lsbuf + 4096 + (part * 256 + wid * 64) * 8);
    }
}

__global__ __launch_bounds__(256, 4) void attn_kernel(
    const u16* __restrict__ Qs, const u16* __restrict__ Ks, const u16* __restrict__ Vt,
    const float* __restrict__ geom, const u64* __restrict__ MBw,
    u16* __restrict__ AO) {
    __shared__ __align__(16) u16 lsKV[2][8192];     // per buf: [0,4096) K-tile, [4096,8192) V-tile
    __shared__ __align__(16) u16 pbuf[4][16][64];   // slot-swizzled P

    const int g = blockIdx.x;
    const int t = (g & 7) * 128 + (g >> 3);         // XCD swizzle (1024 % 8 == 0, bijective)
    const int qb = t & 15;
    const int bhid = t >> 4;
    const int b = bhid >> 4, h = bhid & 15;
    const int q0 = qb * 64;

    const int tid = threadIdx.x, lane = tid & 63, wid = tid >> 6;
    const int l15 = lane & 15, l4 = lane >> 4;
    const int qrow = q0 + wid * 16;
    const size_t bh = (size_t)bhid;

    const u16* qp = Qs + (size_t)(b * 1024 + qrow + l15) * 1024 + h * 64 + l4 * 8;
    bf16x8 aq0 = *(const bf16x8*)qp;
    bf16x8 aq1 = *(const bf16x8*)(qp + 32);

    const float* gbase = geom + (bh * 1024 + qrow + l4 * 4) * 1024 + l15 * 4;
    const u64* mbase = MBw + (bh * 1024 + qrow + l4 * 4) * 16;

    f32x4 o[4] = {};
    float m_run[4], l_run[4];
#pragma unroll
    for (int j = 0; j < 4; ++j) { m_run[j] = -1e30f; l_run[j] = 0.f; }

    // prologue: geometry tile 0 into named buffer A; K/V tile 0 into lsKV[0]
    f32x4 gpA[4], gpB[4];
#pragma unroll
    for (int j = 0; j < 4; ++j) gpA[j] = *(const f32x4*)(gbase + j * 1024);
    stage_kv(&lsKV[0][0], Ks, Vt, b, h, bh, 0, wid, lane);
    __syncthreads();

    const int xr = (l15 & 7) << 1;  // pbuf read-slot xor

#define TILE_BODY(KB, GCUR, GNXT, LSCUR, LSNXT)                                          \
    do {                                                                                 \
        u64 mword[4];                                                                    \
        _Pragma("unroll")                                                                \
        for (int j = 0; j < 4; ++j) mword[j] = mbase[j * 16 + (KB)];                     \
        if ((KB) < 15) {                                                                 \
            _Pragma("unroll")                                                            \
            for (int j = 0; j < 4; ++j)                                                  \
                GNXT[j] = *(const f32x4*)(gbase + j * 1024 + ((KB) + 1) * 64);           \
            stage_kv(LSNXT, Ks, Vt, b, h, bh, (KB) + 1, wid, lane);                      \
        }                                                                                \
        f32x4 s[4];                                                                      \
        _Pragma("unroll")                                                                \
        for (int nf = 0; nf < 4; ++nf) {                                                 \
            const int r = nf * 16 + l15;                                                 \
            const u16* kbp = LSCUR + r * 64;                                             \
            bf16x8 k0 = *(const bf16x8*)(kbp + ((l4 ^ (r & 7)) * 8));                    \
            bf16x8 k1 = *(const bf16x8*)(kbp + (((4 + l4) ^ (r & 7)) * 8));              \
            f32x4 z = {};                                                                \
            z = __builtin_amdgcn_mfma_f32_16x16x32_bf16(aq0, k0, z, 0, 0, 0);            \
            s[nf] = __builtin_amdgcn_mfma_f32_16x16x32_bf16(aq1, k1, z, 0, 0, 0);        \
        }                                                                                \
        _Pragma("unroll")                                                                \
        for (int j = 0; j < 4; ++j) {                                                    \
            unsigned mnib = (unsigned)(mword[j] >> (l15 * 4));                           \
            f32x4 gv = GCUR[j];                                                          \
            _Pragma("unroll")                                                            \
            for (int nf = 0; nf < 4; ++nf) {                                             \
                bool msk = (mnib >> nf) & 1u;                                            \
                s[nf][j] = msk ? -1e30f : (s[nf][j] + __logf(fmaxf(gv[nf], 1e-6f)));     \
            }                                                                            \
        }                                                                                \
        float scl[4];                                                                    \
        _Pragma("unroll")                                                                \
        for (int j = 0; j < 4; ++j) {                                                    \
            float mt = fmaxf(fmaxf(s[0][j], s[1][j]), fmaxf(s[2][j], s[3][j]));          \
            for (int d = 1; d < 16; d <<= 1) mt = fmaxf(mt, __shfl_xor(mt, d, 16));      \
            float mn = fmaxf(m_run[j], mt);                                              \
            scl[j] = __expf(m_run[j] - mn);                                              \
            float rs = 0.f;                                                              \
            for (int nf = 0; nf < 4; ++nf) {                                             \
                float p = __expf(s[nf][j] - mn);                                         \
                s[nf][j] = p;                                                            \
                rs += p;                                                                 \
            }                                                                            \
            for (int d = 1; d < 16; d <<= 1) rs += __shfl_xor(rs, d, 16);                \
            l_run[j] = l_run[j] * scl[j] + rs;                                           \
            m_run[j] = mn;                                                               \
        }                                                                                \
        _Pragma("unroll")                                                                \
        for (int df = 0; df < 4; ++df) {                                                 \
            f32x4 tt = o[df];                                                            \
            for (int j = 0; j < 4; ++j) tt[j] *= scl[j];                                 \
            o[df] = tt;                                                                  \
        }                                                                                \
        _Pragma("unroll")                                                                \
        for (int j = 0; j < 4; ++j) {                                                    \
            int row = l4 * 4 + j;                                                        \
            int slot = l15 ^ ((row & 7) << 1);                                           \
            u64 pk = (u64)f2bf(s[0][j]) | ((u64)f2bf(s[1][j]) << 16) |                   \
                     ((u64)f2bf(s[2][j]) << 32) | ((u64)f2bf(s[3][j]) << 48);            \
            *(u64*)((char*)&pbuf[wid][row][0] + slot * 8) = pk;                          \
        }                                                                                \
        bf16x8 pa0 = *(const bf16x8*)((char*)&pbuf[wid][l15][0] + (((l4 * 2) ^ xr) * 8));\
        bf16x8 pa1 = *(const bf16x8*)((char*)&pbuf[wid][l15][0] + (((8 + l4 * 2) ^ xr) * 8)); \
        _Pragma("unroll")                                                                \
        for (int df = 0; df < 4; ++df) {                                                 \
            const int r = df * 16 + l15;                                                 \
            const u16* vbp = LSCUR + 4096 + r * 64;                                      \
            bf16x8 v0 = *(const bf16x8*)(vbp + ((l4 ^ (r & 7)) * 8));                    \
            bf16x8 v1 = *(const bf16x8*)(vbp + (((4 + l4) ^ (r & 7)) * 8));              \
            o[df] = __builtin_amdgcn_mfma_f32_16x16x32_bf16(pa0, v0, o[df], 0, 0, 0);    \
            o[df] = __builtin_amdgcn_mfma_f32_16x16x32_bf16(pa1, v1, o[df], 0, 0, 0);    \
        }                                                                                \
        __syncthreads();                                                                 \
    } while (0)

    for (int it = 0; it < 8; ++it) {
        const int kb0 = it * 2, kb1 = it * 2 + 1;
        TILE_BODY(kb0, gpA, gpB, (&lsKV[0][0]), (&lsKV[1][0]));
        TILE_BODY(kb1, gpB, gpA, (&lsKV[1][0]), (&lsKV[0][0]));
    }
#undef TILE_BODY

#pragma unroll
    for (int df = 0; df < 4; ++df)
        for (int j = 0; j < 4; ++j) {
            int r = b * 1024 + qrow + l4 * 4 + j;
            int c = h * 64 + df * 16 + l15;
            AO[(size_t)r * 1024 + c] = f2bf(o[df][j] / l_run[j]);
        }
}

// ---------------- LayerNorm over rows of Y (f32) ----------------
__global__ __launch_bounds__(256) void ln_kernel(const float* __restrict__ Y,
                                                 const float* __restrict__ gamma,
                                                 const float* __restrict__ beta,
                                                 float* __restrict__ out) {
    __shared__ float red[8];
    const int r = blockIdx.x, tid = threadIdx.x, lane = tid & 63, wid = tid >> 6;
    float4 v = ((const float4*)(Y + (size_t)r * 1024))[tid];
    float s = v.x + v.y + v.z + v.w;
    float q = v.x * v.x + v.y * v.y + v.z * v.z + v.w * v.w;
    for (int d = 1; d < 64; d <<= 1) {
        s += __shfl_xor(s, d, 64);
        q += __shfl_xor(q, d, 64);
    }
    if (lane == 0) { red[wid] = s; red[4 + wid] = q; }
    __syncthreads();
    float ts = red[0] + red[1] + red[2] + red[3];
    float tq = red[4] + red[5] + red[6] + red[7];
    float mu = ts * (1.f / 1024.f);
    float var = tq * (1.f / 1024.f) - mu * mu;
    float rstd = rsqrtf(var + 1e-5f);
    float4 g = ((const float4*)gamma)[tid];
    float4 be = ((const float4*)beta)[tid];
    float4 ov;
    ov.x = (v.x - mu) * rstd * g.x + be.x;
    ov.y = (v.y - mu) * rstd * g.y + be.y;
    ov.z = (v.z - mu) * rstd * g.z + be.z;
    ov.w = (v.w - mu) * rstd * g.w + be.w;
    ((float4*)(out + (size_t)r * 1024))[tid] = ov;
}

extern "C" void kernel_launch(void* const* d_in, const int* in_sizes, int n_in,
                              void* d_out, int out_size, void* d_ws, size_t ws_size,
                              hipStream_t stream) {
    const float* queries = (const float*)d_in[0];
    const float* keys    = (const float*)d_in[1];
    const float* values  = (const float*)d_in[2];
    const float* geom    = (const float*)d_in[3];
    const void*  mask    = d_in[4];
    const float* Wq = (const float*)d_in[5];  const float* bq = (const float*)d_in[6];
    const float* Wk = (const float*)d_in[7];  const float* bk = (const float*)d_in[8];
    const float* Wv = (const float*)d_in[9];  const float* bv = (const float*)d_in[10];
    const float* Wo = (const float*)d_in[11]; const float* bo = (const float*)d_in[12];
    const float* gamma = (const float*)d_in[13];
    const float* beta  = (const float*)d_in[14];

    char* ws = (char*)d_ws;
    const size_t MB_ = 1024 * 1024;
    u16* XQ  = (u16*)(ws + 0);
    u16* XK  = (u16*)(ws + 8 * MB_);
    u16* XV  = (u16*)(ws + 16 * MB_);
    u16* WQT = (u16*)(ws + 24 * MB_);
    u16* WKT = (u16*)(ws + 26 * MB_);
    u16* WVT = (u16*)(ws + 28 * MB_);
    u16* WOT = (u16*)(ws + 30 * MB_);
    u16* QS  = (u16*)(ws + 32 * MB_);
    u16* KS  = (u16*)(ws + 40 * MB_);
    u16* VT  = (u16*)(ws + 48 * MB_);
    u16* AO  = (u16*)(ws + 56 * MB_);
    u64* MBITS = (u64*)(ws + 16 * MB_);  // reuses XV (dead after qkv_gemm)
    float* Y = (float*)(ws + 0);         // reuses XQ/XK region (dead by then)
    int* FLAG = (int*)(ws + 64 * MB_);

    detect_kernel<<<1, 256, 0, stream>>>((const unsigned char*)mask, FLAG);
    cast3_kernel<<<1024, 256, 0, stream>>>(queries, keys, values, XQ, XK, XV);
    wtrans_kernel<<<dim3(16, 16, 4), dim3(64, 4), 0, stream>>>(Wq, Wk, Wv, Wo, WQT, WKT, WVT, WOT);
    qkv_gemm<<<dim3(8, 32, 3), 256, 0, stream>>>(XQ, XK, XV, WQT, WKT, WVT, bq, bk, bv, QS, KS, VT);
    masknorm_kernel<<<4096, 256, 0, stream>>>(mask, FLAG, MBITS);
    attn_kernel<<<1024, 256, 0, stream>>>(QS, KS, VT, geom, MBITS, AO);
    gemm_out<<<dim3(8, 32), 256, 0, stream>>>(AO, WOT, bo, Y, queries);
    ln_kernel<<<4096, 256, 0, stream>>>(Y, gamma, beta, (float*)d_out);
}